// Round 8
// baseline (134.452 us; speedup 1.0000x reference)
//
#include <hip/hip_runtime.h>
#include <hip/hip_bf16.h>

// out[b,i] = sum_{j<=i} x[b,j] * kernel[i-j]   (causal Toeplitz matmul)
// M=2048, N=K=4096. f32 in/out, bf16 MFMA compute.
//
// R8: A fragments load DIRECTLY from global via a k-blocked transpose
// xbT[k/8][m][8] (coalesced b128 per fragment), eliminating A staging and all
// A ds_reads. R5/R7 showed per-CU slice rate ~1700cyc invariant to resident
// blocks -> LDS unit saturated (~82 LDS instr/slice). Now LDS carries only B
// (~33 instr/slice), double-buffered 256-k chunks, 1 barrier per 4 slices.
// Work mapping / split-K / LPT / combine / reduce identical to R7 (verified).

typedef unsigned short u16;
typedef __attribute__((ext_vector_type(8))) short  bf16x8;
typedef __attribute__((ext_vector_type(8))) unsigned short u16x8;
typedef __attribute__((ext_vector_type(4))) float  f32x4;

#define KDIM 4096
#define NDIM 4096
#define MDIM 2048
#define KREV_STRIDE 4608                    // elems per shifted copy
#define KREV_BYTES  (8 * KREV_STRIDE * 2)   // 73728
#define BSTRIDE 520                         // LDS B copy stride (elems)
#define XB_BYTES  (MDIM * KDIM * 2)         // 16777216
#define PART_BYTES (2 * 256 * 16384 * 4)    // 33554432
#define KBSTRIDE (MDIM * 8)                 // elems per kb plane in xbT (16384)

static __device__ inline u16 f2bf(float f) {
  unsigned u = __builtin_bit_cast(unsigned, f);
  unsigned r = u + 0x7FFFu + ((u >> 16) & 1u);
  return (u16)(r >> 16);
}

static __device__ inline u16x8 cvt8(f32x4 v0, f32x4 v1) {
  u16x8 r;
  r[0]=f2bf(v0[0]); r[1]=f2bf(v0[1]); r[2]=f2bf(v0[2]); r[3]=f2bf(v0[3]);
  r[4]=f2bf(v1[0]); r[5]=f2bf(v1[1]); r[6]=f2bf(v1[2]); r[7]=f2bf(v1[3]);
  return r;
}

static __device__ inline void async_copy16(const void* g, void* l) {
  __builtin_amdgcn_global_load_lds((const __attribute__((address_space(1))) void*)g,
                                   (__attribute__((address_space(3))) void*)l,
                                   16, 0, 0);
}

// prep: blocks [0, conv_blocks) build xbT[kb][m][8] = bf16(x[m][kb*8+j])
// via LDS-tiled 64x64 transpose; last 18 blocks build 8 shifted krev copies.
__global__ __launch_bounds__(256) void prep(const float* __restrict__ x,
                                            const float* __restrict__ kern,
                                            u16* __restrict__ xbT,
                                            u16* __restrict__ krevs,
                                            int conv_blocks) {
  __shared__ u16 tile[64][72];              // 9216 B; stride 72 -> conflict-free phases
  int kb = (int)blockIdx.x - conv_blocks;
  if (kb >= 0) {
    int u = kb * 256 + threadIdx.x;         // 0..4607
    for (int a = 0; a < 8; ++a) {
      int t = u + a - 8;
      u16 v = 0;
      if (t >= 0 && t <= 4095) v = f2bf(kern[4095 - t]);
      krevs[a * KREV_STRIDE + u] = v;
    }
  } else {
    const int m0 = ((int)blockIdx.x & 31) * 64;
    const int k0 = ((int)blockIdx.x >> 5) * 64;
    const int t  = threadIdx.x;
    {
      int r  = t >> 2;
      int kc = (t & 3) * 16;
      const f32x4* px = (const f32x4*)(x + (size_t)(m0 + r) * KDIM + k0 + kc);
      f32x4 v0 = px[0], v1 = px[1], v2 = px[2], v3 = px[3];
      u16x8 a = cvt8(v0, v1), b = cvt8(v2, v3);
      *(u16x8*)&tile[r][kc]     = a;
      *(u16x8*)&tile[r][kc + 8] = b;
    }
    __syncthreads();
    {
      int kbb = t >> 5;                     // 0..7
      int mm  = t & 31;
      for (int hh = 0; hh < 2; ++hh) {
        int m = mm + hh * 32;
        u16x8 v = *(const u16x8*)&tile[m][kbb * 8];
        *(u16x8*)(xbT + (size_t)(k0 / 8 + kbb) * KBSTRIDE + (size_t)(m0 + m) * 8) = v;
      }
    }
  }
}

// Sum the two K-half partials of each split tile into out.
__global__ __launch_bounds__(256) void reduce_parts(const float* __restrict__ partials,
                                                    float* __restrict__ out) {
  const int rb = (int)blockIdx.x;
  const int tileIdx = rb >> 1;
  const int hh = rb & 1;
  const int ct = 16 + (tileIdx >> 4);
  const int mt = tileIdx & 15;
  const f32x4* p0 = (const f32x4*)(partials + (size_t)tileIdx * 16384);
  const f32x4* p1 = (const f32x4*)(partials + (size_t)(256 + tileIdx) * 16384);
  for (int i = 0; i < 8; ++i) {
    int chunk = hh * 2048 + (int)threadIdx.x + i * 256;
    int row = chunk >> 5;
    int c4  = chunk & 31;
    f32x4 v = p0[chunk];
    f32x4 w = p1[chunk];
    v[0]+=w[0]; v[1]+=w[1]; v[2]+=w[2]; v[3]+=w[3];
    *(f32x4*)(out + (size_t)(mt * 128 + row) * NDIM + ct * 128 + c4 * 4) = v;
  }
}

template <bool CONV>
__global__ __launch_bounds__(512, 4) void toeplitz_gemm(const void* __restrict__ Av,
                                                        const u16* __restrict__ krevs,
                                                        float* __restrict__ out,
                                                        float* __restrict__ partials,
                                                        int split_mode) {
  __shared__ __align__(16) char smem[36864];
  u16*   B_all = (u16*)smem;                // 2 bufs x 4160 elems (16640 B)
  f32x4* ep    = (f32x4*)smem;              // combine overlay (36848 B)

  const int tid  = threadIdx.x;
  const int w    = tid >> 6;        // 0..7
  const int g    = w >> 2;          // K-group 0..1
  const int wl   = w & 3;
  const int lane = tid & 63;
  const int lane16 = lane & 15;
  const int quad   = lane >> 4;
  const int wm = wl >> 1;
  const int wn = wl & 1;

  // ---- block -> work mapping (R7, verified) ----
  int ct, mt, s0, cnt, h = 0, split = 0;
  const int b = (int)blockIdx.x;
  if (split_mode) {
    if (b < 640) {
      int p = b / 80, r = b % 80;
      if (r < 48) {
        if (r < 32) { split = 1; ct = 31 - 2 * p; h = r >> 4; mt = r & 15; }
        else        { split = 0; ct = 15 - p;     mt = r - 32; }
      } else        { split = 1; ct = 30 - 2 * p; int r2 = r - 48; h = r2 >> 4; mt = r2 & 15; }
    } else {
      int j = b - 640; split = 0; ct = 7 - (j >> 4); mt = j & 15;
    }
  } else {
    const int rank = (b < 256) ? b : 511 - (b & 255);
    ct = 31 - (rank >> 4); mt = rank & 15;
  }
  if (split) { s0 = h * (ct + 1); cnt = ct + 1; }
  else       { s0 = 0;            cnt = 2 * ct + 2; }

  const int n0 = ct * 128;
  const int m0 = mt * 128;
  const int W  = 3968 - n0;                 // B window base (8-aligned)

  int boff[4];
  for (int fn = 0; fn < 4; ++fn) {
    int n_g = n0 + wn * 64 + fn * 16 + lane16;
    int s0f = 4095 - n_g + quad * 8;
    int a   = s0f & 7;
    boff[fn] = a * BSTRIDE + (s0f - a + 8 - W);
  }

  f32x4 acc[4][4] = {};

  const u16*   xbT = (const u16*)Av;        // [kb][m][8]
  const float* xf  = (const float*)Av;
  // A-frag: af(fm) at kb = sg*8 + kk*4 + quad, elems (m0+wm*64+fm*16+lane16)*8..+8
  const u16* abase = xbT + (size_t)(m0 + wm * 64 + lane16) * 8 + (size_t)quad * KBSTRIDE;

  auto stageB = [&](int c) {
    async_copy16(krevs + w * KREV_STRIDE + W + s0 * 64 + c * 256 + (lane << 3),
                 &B_all[(c & 1) * 4160 + w * BSTRIDE]);
  };

  const int T   = (cnt + 1) >> 1;           // iterations (2 slices each)
  const int nch = (T + 1) >> 1;             // 256-k B chunks

  stageB(0);

  for (int t = 0; t < T; ++t) {
    if (!(t & 1)) {
      __syncthreads();                      // drain stage(chunk t/2); prior buf reads done
      int c1 = (t >> 1) + 1;
      if (c1 < nch) stageB(c1);
    }
    if (2 * t + g < cnt) {
      const u16* Bb  = B_all + ((t >> 1) & 1) * 4160;
      const int  ksl = (t & 1) * 128 + g * 64;
      const int  sg  = s0 + 2 * t + g;      // global 64-k slice index
      for (int kk = 0; kk < 2; ++kk) {
        bf16x8 af[4];
        if constexpr (CONV) {
          for (int fm = 0; fm < 4; ++fm) {
            const float* px = xf + (size_t)(m0 + wm * 64 + fm * 16 + lane16) * KDIM
                                 + sg * 64 + kk * 32 + quad * 8;
            u16x8 r = cvt8(*(const f32x4*)px, *(const f32x4*)(px + 4));
            af[fm] = *(bf16x8*)&r;
          }
        } else {
          const u16* ap = abase + (size_t)(sg * 8 + kk * 4) * KBSTRIDE;
          for (int fm = 0; fm < 4; ++fm)
            af[fm] = *(const bf16x8*)(ap + fm * 128);
        }
        bf16x8 bf[4];
        for (int fn = 0; fn < 4; ++fn)
          bf[fn] = *(const bf16x8*)(&Bb[boff[fn] + ksl + kk * 32]);
        for (int fm = 0; fm < 4; ++fm)
          for (int fn = 0; fn < 4; ++fn)
            acc[fm][fn] = __builtin_amdgcn_mfma_f32_16x16x32_bf16(af[fm], bf[fn], acc[fm][fn], 0, 0, 0);
      }
    }
  }

  // combine: group1 partials -> group0 via LDS (2 rounds), R7-verbatim
  const int j = tid & 255;
  for (int r = 0; r < 2; ++r) {
    __syncthreads();
    if (g == 1) {
      for (int fm2 = 0; fm2 < 2; ++fm2)
        for (int fn = 0; fn < 4; ++fn)
          ep[j * 9 + fm2 * 4 + fn] = acc[r * 2 + fm2][fn];
    }
    __syncthreads();
    if (g == 0) {
      for (int fm2 = 0; fm2 < 2; ++fm2)
        for (int fn = 0; fn < 4; ++fn)
          acc[r * 2 + fm2][fn] += ep[j * 9 + fm2 * 4 + fn];
    }
  }

  // epilogue (group 0): C/D layout col=lane&15, row=quad*4+r
  if (g == 0) {
    if (split) {
      float* pp = partials + (size_t)(h * 256 + (ct - 16) * 16 + mt) * 16384;
      for (int fm = 0; fm < 4; ++fm) {
        int rl = wm * 64 + fm * 16 + quad * 4;
        for (int fn = 0; fn < 4; ++fn) {
          int cl = wn * 64 + fn * 16 + lane16;
          for (int r = 0; r < 4; ++r)
            pp[(rl + r) * 128 + cl] = acc[fm][fn][r];
        }
      }
    } else {
      for (int fm = 0; fm < 4; ++fm) {
        int row_base = m0 + wm * 64 + fm * 16 + quad * 4;
        for (int fn = 0; fn < 4; ++fn) {
          int col = n0 + wn * 64 + fn * 16 + lane16;
          for (int r = 0; r < 4; ++r)
            out[(size_t)(row_base + r) * NDIM + col] = acc[fm][fn][r];
        }
      }
    }
  }
}

extern "C" void kernel_launch(void* const* d_in, const int* in_sizes, int n_in,
                              void* d_out, int out_size, void* d_ws, size_t ws_size,
                              hipStream_t stream) {
  const float* x    = (const float*)d_in[0];
  const float* kern = (const float*)d_in[1];
  float* out = (float*)d_out;

  u16*   krevs    = (u16*)d_ws;
  u16*   xbT      = (u16*)((char*)d_ws + KREV_BYTES);
  float* partials = (float*)((char*)d_ws + KREV_BYTES + XB_BYTES);

  const size_t need_fast  = (size_t)KREV_BYTES + XB_BYTES;
  const size_t need_split = need_fast + PART_BYTES;

  if (ws_size >= need_split) {
    prep<<<2048 + 18, 256, 0, stream>>>(x, kern, xbT, krevs, 2048);
    toeplitz_gemm<false><<<768, 512, 0, stream>>>(xbT, krevs, out, partials, 1);
    reduce_parts<<<512, 256, 0, stream>>>(partials, out);
  } else if (ws_size >= need_fast) {
    prep<<<2048 + 18, 256, 0, stream>>>(x, kern, xbT, krevs, 2048);
    toeplitz_gemm<false><<<512, 512, 0, stream>>>(xbT, krevs, out, partials, 0);
  } else {
    prep<<<18, 256, 0, stream>>>(x, kern, xbT, krevs, 0);
    toeplitz_gemm<true><<<512, 512, 0, stream>>>(x, krevs, out, partials, 0);
  }
}